// Round 1
// 920.775 us; speedup vs baseline: 1.2114x; 1.2114x over previous
//
#include <hip/hip_runtime.h>
#include <hip/hip_bf16.h>

typedef __bf16 bf16x8 __attribute__((ext_vector_type(8)));
typedef float floatx4 __attribute__((ext_vector_type(4)));

#define GLOBAL_AS __attribute__((address_space(1)))
#define LDS_AS __attribute__((address_space(3)))

constexpr int M_NODES = 50000;
constexpr int HSZ  = 256;
constexpr int KDIM = 1536;   // 256 (x part) + 1280 (h_flat part)
constexpr int NDIM = 2048;   // 8 gates (f0..f4, i, o, u) * 256
constexpr int BM = 128, BN = 256, BK = 64;
constexpr int MT = (M_NODES + BM - 1) / BM;  // 391
constexpr int NT = NDIM / BN;                // 8
constexpr size_t WCT_BYTES = (size_t)NDIM * KDIM * 2;       // 6.29 MB
constexpr size_t A_BYTES   = (size_t)M_NODES * KDIM * 2;    // 153.6 MB

// ---------------- weight fusion: bf16 WcT[n][k], N-major ----------------
// NEW layout for BN=256: n = tb*256 + u*128 + s*16 + tl, u in {0,1} = wave-col,
// gate s: 0..4 = f_child_s, 5=i, 6=o, 7=u; unit t = tb*32 + u*16 + tl.
// x-rows (k<256) of f columns carry 2*W_f_in (reference adds f_input twice).
__global__ __launch_bounds__(256) void prep_weights(
    const float* __restrict__ W_iou_in, const float* __restrict__ W_f_in,
    const float* __restrict__ W_aggr_iou, const float* __restrict__ W_aggr_f,
    __bf16* __restrict__ WcT)
{
  int idx = blockIdx.x * 256 + threadIdx.x;
  if (idx >= NDIM * KDIM) return;
  int n = idx / KDIM, k = idx - n * KDIM;
  int tb = n >> 8;
  int u  = (n >> 7) & 1;
  int s  = (n >> 4) & 7;
  int tl = n & 15;
  int t  = tb * 32 + u * 16 + tl;
  float v;
  if (k < 256) {
    if (s < 5) v = 2.0f * W_f_in[k * 256 + t];
    else       v = W_iou_in[k * 768 + (s - 5) * 256 + t];
  } else {
    int kh = k - 256;
    if (s < 5) v = W_aggr_f[kh * 1280 + s * 256 + t];
    else       v = W_aggr_iou[kh * 768 + (s - 5) * 256 + t];
  }
  WcT[idx] = (__bf16)v;
}

// ---------------- A fusion: bf16 Abf[r][0:256]=x*mask, [256:1536]=nh ----------------
__global__ __launch_bounds__(256) void prep_A(
    const float* __restrict__ x, const float* __restrict__ xmask,
    const float* __restrict__ nh, __bf16* __restrict__ Abf)
{
  int ci = blockIdx.x * 256 + threadIdx.x;       // one 8-element chunk
  if (ci >= M_NODES * (KDIM / 8)) return;
  int row = ci / (KDIM / 8);
  int kc  = ci - row * (KDIM / 8);
  const float* src;
  float sc;
  if (kc < 32) { src = x  + (size_t)row * 256  + kc * 8;        sc = xmask[row]; }
  else         { src = nh + (size_t)row * 1280 + (size_t)(kc - 32) * 8; sc = 1.0f; }
  float4 f0 = *(const float4*)src;
  float4 f1 = *(const float4*)(src + 4);
  bf16x8 v;
  v[0] = (__bf16)(f0.x * sc); v[1] = (__bf16)(f0.y * sc);
  v[2] = (__bf16)(f0.z * sc); v[3] = (__bf16)(f0.w * sc);
  v[4] = (__bf16)(f1.x * sc); v[5] = (__bf16)(f1.y * sc);
  v[6] = (__bf16)(f1.z * sc); v[7] = (__bf16)(f1.w * sc);
  *(bf16x8*)(Abf + (size_t)row * KDIM + kc * 8) = v;
}

// fast sigmoid/tanh: v_rcp_f32 (~1ulp) instead of IEEE divide (no -ffast-math here)
__device__ __forceinline__ float sigm(float v) {
  return __builtin_amdgcn_rcpf(1.0f + __expf(-v));
}
__device__ __forceinline__ float tanh_(float v) {
  return 2.0f * __builtin_amdgcn_rcpf(1.0f + __expf(-2.0f * v)) - 1.0f;
}

// ---------------- main GEMM + LSTM epilogue ----------------
// 128x256 tile, BK=64, 4 waves in 2x2 grid, each wave owns a 64x128 sub-tile
// (acc[4][8] = 128 VGPR). LDS rows are 64 bf16 = 128 B = 8 chunks of 16 B.
// Swizzle: physical chunk p = logical chunk c ^ (row & 7)  (involution), so
// ds_read_b128 per 8-lane group hits 8 distinct 16B bank-groups (conflict-free).
// global_load_lds writes linearly (wave base + lane*16); the SOURCE address is
// pre-swizzled: lane holding phys chunk p of row r fetches logical chunk p^(r&7).
template <bool FROM_ABF>
__global__ __launch_bounds__(256, 2) void gemm_treelstm2(
    const __bf16* __restrict__ Abf, const __bf16* __restrict__ WcT,
    const float* __restrict__ x, const float* __restrict__ xmask,
    const float* __restrict__ nh, const float* __restrict__ nc,
    const float* __restrict__ b_iou, const float* __restrict__ b_f,
    const float* __restrict__ b_aiou, const float* __restrict__ b_af,
    float* __restrict__ out)
{
  __shared__ __bf16 ldsA[BM * BK];   // 16 KB
  __shared__ __bf16 ldsB[BN * BK];   // 32 KB

  // bijective XCD chunking: 3128 = 8 * 391; each XCD gets 391 consecutive wgids
  // (~49 m-tiles x all 8 n-tiles -> A-panels stay L2-local per XCD).
  const int bid  = blockIdx.x;
  const int wgid = (bid & 7) * (MT * NT / 8) + (bid >> 3);
  const int bn   = wgid & 7;          // n-tile (256 cols = 8 gates x 32 t)
  const int m0   = (wgid >> 3) * BM;

  const int tid  = threadIdx.x;
  const int lane = tid & 63;
  const int w    = tid >> 6;
  const int wr   = w >> 1, wc = w & 1;   // 2x2 wave grid
  const int frow = lane & 15, kq = lane >> 4;
  const int l8   = lane >> 3, pch = lane & 7;   // staging: dest row sub-idx / phys chunk

  // ---- staging addresses ----
  const __bf16* pA[4];
  const __bf16* pB[8];
  const float* xp[4]; const float* nhp[4]; float am[4]; int ac[4]; int arl[4];
#pragma unroll
  for (int j = 0; j < 4; ++j) {
    const int rl = w * 32 + j * 8 + l8;          // local A row 0..127
    const int c  = pch ^ (rl & 7);               // logical chunk for this lane's slot
    int gr = m0 + rl; if (gr >= M_NODES) gr = M_NODES - 1;
    if constexpr (FROM_ABF) {
      pA[j] = Abf + (size_t)gr * KDIM + c * 8;
    } else {
      arl[j] = rl; ac[j] = c;
      xp[j]  = x  + (size_t)gr * 256;
      nhp[j] = nh + (size_t)gr * 1280 - 256;
      am[j]  = xmask[gr];
    }
  }
#pragma unroll
  for (int j = 0; j < 8; ++j) {
    const int rl = w * 64 + j * 8 + l8;          // local B row 0..255
    const int c  = pch ^ (rl & 7);
    pB[j] = WcT + (size_t)(bn * BN + rl) * KDIM + c * 8;
  }

  // ---- fragment read offsets (elements), swizzled ----
  int aoff[4][2], boff[8][2];
#pragma unroll
  for (int mf = 0; mf < 4; ++mf) {
    const int ra = wr * 64 + mf * 16 + frow;
#pragma unroll
    for (int ks = 0; ks < 2; ++ks)
      aoff[mf][ks] = ra * BK + (((ks * 4 + kq) ^ (ra & 7)) * 8);
  }
#pragma unroll
  for (int nf = 0; nf < 8; ++nf) {
    const int rb = wc * 128 + nf * 16 + frow;
#pragma unroll
    for (int ks = 0; ks < 2; ++ks)
      boff[nf][ks] = rb * BK + (((ks * 4 + kq) ^ (rb & 7)) * 8);
  }

  floatx4 acc[4][8];
#pragma unroll
  for (int i = 0; i < 4; ++i)
#pragma unroll
    for (int j = 0; j < 8; ++j) acc[i][j] = (floatx4)(0.0f);

  for (int kt = 0; kt < KDIM / BK; ++kt) {
    __syncthreads();   // WAR: all waves done reading LDS
    if constexpr (FROM_ABF) {
#pragma unroll
      for (int j = 0; j < 4; ++j) {
        __builtin_amdgcn_global_load_lds((const GLOBAL_AS void*)pA[j],
            (LDS_AS void*)((LDS_AS char*)(LDS_AS __bf16*)ldsA + (w * 32 + j * 8) * 128), 16, 0, 0);
        pA[j] += BK;
      }
#pragma unroll
      for (int j = 0; j < 8; ++j) {
        __builtin_amdgcn_global_load_lds((const GLOBAL_AS void*)pB[j],
            (LDS_AS void*)((LDS_AS char*)(LDS_AS __bf16*)ldsB + (w * 64 + j * 8) * 128), 16, 0, 0);
        pB[j] += BK;
      }
    } else {
      const int k0base = kt * BK;
#pragma unroll
      for (int j = 0; j < 4; ++j) {
        const int k0 = k0base + ac[j] * 8;
        const float* src = (k0 < 256) ? (xp[j] + k0) : (nhp[j] + k0);
        const float sc   = (k0 < 256) ? am[j] : 1.0f;
        float4 f0 = *(const float4*)src;
        float4 f1 = *(const float4*)(src + 4);
        bf16x8 v;
        v[0] = (__bf16)(f0.x * sc); v[1] = (__bf16)(f0.y * sc);
        v[2] = (__bf16)(f0.z * sc); v[3] = (__bf16)(f0.w * sc);
        v[4] = (__bf16)(f1.x * sc); v[5] = (__bf16)(f1.y * sc);
        v[6] = (__bf16)(f1.z * sc); v[7] = (__bf16)(f1.w * sc);
        *(bf16x8*)&ldsA[arl[j] * BK + pch * 8] = v;
      }
#pragma unroll
      for (int j = 0; j < 8; ++j) {
        bf16x8 vb = *(const bf16x8*)pB[j];
        *(bf16x8*)&ldsB[(w * 64 + j * 8 + l8) * BK + pch * 8] = vb;
        pB[j] += BK;
      }
    }
    __syncthreads();   // includes vmcnt/lgkm drain: tile resident

#pragma unroll
    for (int ks = 0; ks < 2; ++ks) {
      bf16x8 a0 = *(const bf16x8*)&ldsA[aoff[0][ks]];
      bf16x8 a1 = *(const bf16x8*)&ldsA[aoff[1][ks]];
      bf16x8 a2 = *(const bf16x8*)&ldsA[aoff[2][ks]];
      bf16x8 a3 = *(const bf16x8*)&ldsA[aoff[3][ks]];
#pragma unroll
      for (int nf = 0; nf < 8; ++nf) {
        bf16x8 b = *(const bf16x8*)&ldsB[boff[nf][ks]];
        acc[0][nf] = __builtin_amdgcn_mfma_f32_16x16x32_bf16(a0, b, acc[0][nf], 0, 0, 0);
        acc[1][nf] = __builtin_amdgcn_mfma_f32_16x16x32_bf16(a1, b, acc[1][nf], 0, 0, 0);
        acc[2][nf] = __builtin_amdgcn_mfma_f32_16x16x32_bf16(a2, b, acc[2][nf], 0, 0, 0);
        acc[3][nf] = __builtin_amdgcn_mfma_f32_16x16x32_bf16(a3, b, acc[3][nf], 0, 0, 0);
      }
    }
  }

  // ---- register-local epilogue: acc[mf][s][j] = gate s, row r, unit t ----
  const int t = bn * 32 + wc * 16 + frow;
  float baf5[5];
#pragma unroll
  for (int s = 0; s < 5; ++s) baf5[s] = b_af[s * 256 + t];
  const float bf2 = 2.0f * b_f[t];
  float biou3[3], baiou3[3];
#pragma unroll
  for (int g = 0; g < 3; ++g) {
    biou3[g]  = b_iou[g * 256 + t];
    baiou3[g] = b_aiou[g * 256 + t];
  }

#pragma unroll
  for (int mf = 0; mf < 4; ++mf) {
#pragma unroll
    for (int j = 0; j < 4; ++j) {
      const int r = m0 + wr * 64 + mf * 16 + kq * 4 + j;
      if (r >= M_NODES) continue;
      const float mk = xmask[r];
      float ca = 0.0f;
#pragma unroll
      for (int s = 0; s < 5; ++s) {
        const float fa = acc[mf][s][j] + baf5[s] + mk * bf2;
        ca += sigm(fa) * nc[((size_t)r * 5 + s) * 256 + t];
      }
      const float iv = sigm(acc[mf][5][j] + mk * biou3[0] + baiou3[0]);
      const float ov = sigm(acc[mf][6][j] + mk * biou3[1] + baiou3[1]);
      const float uv = tanh_(acc[mf][7][j] + mk * biou3[2] + baiou3[2]);
      const float c  = iv * uv + ca;
      const float h  = ov * tanh_(c);
      out[(size_t)r * HSZ + t] = h;
      out[(size_t)M_NODES * HSZ + (size_t)r * HSZ + t] = c;
    }
  }
}

extern "C" void kernel_launch(void* const* d_in, const int* in_sizes, int n_in,
                              void* d_out, int out_size, void* d_ws, size_t ws_size,
                              hipStream_t stream)
{
  const float* x      = (const float*)d_in[0];
  const float* xmask  = (const float*)d_in[1];
  const float* nh     = (const float*)d_in[2];
  const float* nc     = (const float*)d_in[3];
  const float* W_iou  = (const float*)d_in[4];
  const float* b_iou  = (const float*)d_in[5];
  const float* W_f    = (const float*)d_in[6];
  const float* b_f    = (const float*)d_in[7];
  const float* W_aiou = (const float*)d_in[8];
  const float* b_aiou = (const float*)d_in[9];
  const float* W_af   = (const float*)d_in[10];
  const float* b_af   = (const float*)d_in[11];
  __bf16* WcT = (__bf16*)d_ws;
  float* out  = (float*)d_out;

  prep_weights<<<(NDIM * KDIM + 255) / 256, 256, 0, stream>>>(W_iou, W_f, W_aiou, W_af, WcT);

  if (ws_size >= WCT_BYTES + A_BYTES) {
    __bf16* Abf = (__bf16*)((char*)d_ws + WCT_BYTES);
    prep_A<<<(M_NODES * (KDIM / 8) + 255) / 256, 256, 0, stream>>>(x, xmask, nh, Abf);
    gemm_treelstm2<true><<<dim3(MT * NT), 256, 0, stream>>>(
        Abf, WcT, x, xmask, nh, nc, b_iou, b_f, b_aiou, b_af, out);
  } else {
    gemm_treelstm2<false><<<dim3(MT * NT), 256, 0, stream>>>(
        nullptr, WcT, x, xmask, nh, nc, b_iou, b_f, b_aiou, b_af, out);
  }
}

// Round 3
// 907.438 us; speedup vs baseline: 1.2292x; 1.0147x over previous
//
#include <hip/hip_runtime.h>
#include <hip/hip_bf16.h>

typedef __bf16 bf16x8 __attribute__((ext_vector_type(8)));
typedef float floatx4 __attribute__((ext_vector_type(4)));

#define GLOBAL_AS __attribute__((address_space(1)))
#define LDS_AS __attribute__((address_space(3)))

constexpr int M_NODES = 50000;
constexpr int HSZ  = 256;
constexpr int KDIM = 1536;   // 256 (x part) + 1280 (h_flat part)
constexpr int NDIM = 2048;   // 8 gates (f0..f4, i, o, u) * 256
constexpr size_t WCT_BYTES = (size_t)NDIM * KDIM * 2;       // 6.29 MB
constexpr size_t A_BYTES   = (size_t)M_NODES * KDIM * 2;    // 153.6 MB

// main kernel geometry: 256x256 tile, 8 waves (4Mx2N), BK=32, ring-3 LDS
constexpr int BM = 256, BN = 256, BK = 32;
constexpr int MT = (M_NODES + BM - 1) / BM;   // 196
constexpr int NT = NDIM / BN;                 // 8
constexpr int NKT = KDIM / BK;                // 48
constexpr int SLOT  = BM * BK * 2 + BN * BK * 2;  // 32 KB per ring slot
constexpr int BOFF0 = BM * BK * 2;                // B region offset in slot (16 KB)

// ---------------- weight fusion: bf16 WcT[n][k], N-major ----------------
// n = tb*256 + wc*128 + s*16 + tl ; gate s: 0..4 = f_child_s, 5=i, 6=o, 7=u;
// unit t = tb*32 + wc*16 + tl. x-rows (k<256) of f columns carry 2*W_f_in.
__global__ __launch_bounds__(256) void prep_weights(
    const float* __restrict__ W_iou_in, const float* __restrict__ W_f_in,
    const float* __restrict__ W_aggr_iou, const float* __restrict__ W_aggr_f,
    __bf16* __restrict__ WcT)
{
  int idx = blockIdx.x * 256 + threadIdx.x;
  if (idx >= NDIM * KDIM) return;
  int n = idx / KDIM, k = idx - n * KDIM;
  int tb = n >> 8;
  int u  = (n >> 7) & 1;
  int s  = (n >> 4) & 7;
  int tl = n & 15;
  int t  = tb * 32 + u * 16 + tl;
  float v;
  if (k < 256) {
    if (s < 5) v = 2.0f * W_f_in[k * 256 + t];
    else       v = W_iou_in[k * 768 + (s - 5) * 256 + t];
  } else {
    int kh = k - 256;
    if (s < 5) v = W_aggr_f[kh * 1280 + s * 256 + t];
    else       v = W_aggr_iou[kh * 768 + (s - 5) * 256 + t];
  }
  WcT[idx] = (__bf16)v;
}

// ---------------- A fusion: bf16 Abf[r][0:256]=x*mask, [256:1536]=nh ----------------
__global__ __launch_bounds__(256) void prep_A(
    const float* __restrict__ x, const float* __restrict__ xmask,
    const float* __restrict__ nh, __bf16* __restrict__ Abf)
{
  int ci = blockIdx.x * 256 + threadIdx.x;       // one 8-element chunk
  if (ci >= M_NODES * (KDIM / 8)) return;
  int row = ci / (KDIM / 8);
  int kc  = ci - row * (KDIM / 8);
  const float* src;
  float sc;
  if (kc < 32) { src = x  + (size_t)row * 256  + kc * 8;        sc = xmask[row]; }
  else         { src = nh + (size_t)row * 1280 + (size_t)(kc - 32) * 8; sc = 1.0f; }
  float4 f0 = *(const float4*)src;
  float4 f1 = *(const float4*)(src + 4);
  bf16x8 v;
  v[0] = (__bf16)(f0.x * sc); v[1] = (__bf16)(f0.y * sc);
  v[2] = (__bf16)(f0.z * sc); v[3] = (__bf16)(f0.w * sc);
  v[4] = (__bf16)(f1.x * sc); v[5] = (__bf16)(f1.y * sc);
  v[6] = (__bf16)(f1.z * sc); v[7] = (__bf16)(f1.w * sc);
  *(bf16x8*)(Abf + (size_t)row * KDIM + kc * 8) = v;
}

__device__ __forceinline__ float sigm(float v) {
  return __builtin_amdgcn_rcpf(1.0f + __expf(-v));
}
__device__ __forceinline__ float tanh_(float v) {
  return 2.0f * __builtin_amdgcn_rcpf(1.0f + __expf(-2.0f * v)) - 1.0f;
}

// ---------------- main GEMM + LSTM epilogue: counted-vmcnt ring-3 pipeline ----------------
// 8 waves, per-wave 64(M)x128(N) so each thread holds all 8 gates for its t.
// LDS: 3 slots x (A 16KB + B 16KB). K-tile kt lives in slot kt%3.
// Per K-tile: [vmcnt(4); s_barrier] then 2 phases (mf{0,1}, mf{2,3}), B-frags
// persist in registers across the pair. Stage of kt+2 issues 2 loads per phase.
// vmcnt is NEVER drained to 0 inside the loop (2 half-tiles stay in flight).
// Swizzle: 64B rows, phys 16B-chunk p = c ^ (row&3) -> conflict-free ds_read_b128;
// staging pre-swizzles the GLOBAL source (LDS dest stays linear, rule #21).
__global__ __launch_bounds__(512, 2) void gemm_8ph(
    const __bf16* __restrict__ Abf, const __bf16* __restrict__ WcT,
    const float* __restrict__ xmask, const float* __restrict__ nc,
    const float* __restrict__ b_iou, const float* __restrict__ b_f,
    const float* __restrict__ b_aiou, const float* __restrict__ b_af,
    float* __restrict__ out)
{
  __shared__ __attribute__((aligned(128))) char lds[3 * SLOT];   // 96 KB

  // bijective XCD chunking: 1568 = 8 * 196
  const int bid  = blockIdx.x;
  const int wgid = (bid & 7) * (MT * NT / 8) + (bid >> 3);
  const int bn   = wgid & 7;
  const int m0   = (wgid >> 3) * BM;

  const int tid  = threadIdx.x;
  const int lane = tid & 63;
  const int w    = tid >> 6;          // 0..7
  const int wr   = w >> 1;            // 0..3  (M position, 64 rows each)
  const int wc   = w & 1;             // 0..1  (N position, 128 cols each)
  const int frow = lane & 15, kq = lane >> 4;

  // ---- staging: per-lane global source, linear LDS dest ----
  const int srow = lane >> 2;                  // 0..15 (row within 1KB issue)
  const int sch  = (lane & 3) ^ (srow & 3);    // pre-swizzled logical chunk
  int arL = m0 + w * 16 + srow;        if (arL >= M_NODES) arL = M_NODES - 1;
  int arH = m0 + 128 + w * 16 + srow;  if (arH >= M_NODES) arH = M_NODES - 1;
  const __bf16* pAL = Abf + (size_t)arL * KDIM + sch * 8;
  const __bf16* pAH = Abf + (size_t)arH * KDIM + sch * 8;
  const __bf16* pBL = WcT + (size_t)(bn * BN + w * 16 + srow) * KDIM + sch * 8;
  const __bf16* pBH = WcT + (size_t)(bn * BN + 128 + w * 16 + srow) * KDIM + sch * 8;
  LDS_AS char* ldsb = (LDS_AS char*)lds;
  const int dAL = w * 1024;
  const int dAH = 8192 + w * 1024;
  const int dBL = BOFF0 + w * 1024;
  const int dBH = BOFF0 + 8192 + w * 1024;

  // ---- fragment read offsets (bytes, slot-relative), same swizzle ----
  const int swz = (kq ^ (frow & 3)) << 4;
  int aoff[4], boff[8];
#pragma unroll
  for (int mf = 0; mf < 4; ++mf) aoff[mf] = (wr * 64 + mf * 16 + frow) * 64 + swz;
#pragma unroll
  for (int nf = 0; nf < 8; ++nf) boff[nf] = BOFF0 + (wc * 128 + nf * 16 + frow) * 64 + swz;

  floatx4 acc[4][8];
#pragma unroll
  for (int i = 0; i < 4; ++i)
#pragma unroll
    for (int j = 0; j < 8; ++j) acc[i][j] = (floatx4)(0.0f);

#define STAGE_LO(koff, sl) do { \
    __builtin_amdgcn_global_load_lds((const GLOBAL_AS void*)(pAL + (koff)), \
        (LDS_AS void*)(ldsb + (sl) + dAL), 16, 0, 0); \
    __builtin_amdgcn_global_load_lds((const GLOBAL_AS void*)(pBL + (koff)), \
        (LDS_AS void*)(ldsb + (sl) + dBL), 16, 0, 0); \
  } while (0)
#define STAGE_HI(koff, sl) do { \
    __builtin_amdgcn_global_load_lds((const GLOBAL_AS void*)(pAH + (koff)), \
        (LDS_AS void*)(ldsb + (sl) + dAH), 16, 0, 0); \
    __builtin_amdgcn_global_load_lds((const GLOBAL_AS void*)(pBH + (koff)), \
        (LDS_AS void*)(ldsb + (sl) + dBH), 16, 0, 0); \
  } while (0)

  // prologue: stage kt0 -> slot0, kt1 -> slot1 (8 loads outstanding)
  STAGE_LO(0, 0);        STAGE_HI(0, 0);
  STAGE_LO(BK, SLOT);    STAGE_HI(BK, SLOT);

  int slotC = 0, slotN = SLOT, slotT = 2 * SLOT;
  for (int kt = 0; kt < NKT; ++kt) {
    const int kS = (kt + 2 < NKT ? kt + 2 : NKT - 1) * BK;   // clamp: redundant, never read
    // kt's 4 loads done (kt+1's 4 may remain in flight) -> barrier publishes slotC
    asm volatile("s_waitcnt vmcnt(4)" ::: "memory");
    __builtin_amdgcn_s_barrier();
    asm volatile("" ::: "memory");

    // ---- phase A: mf 0,1 ; load all B frags (persist through phase B) ----
    bf16x8 b[8];
#pragma unroll
    for (int nf = 0; nf < 8; ++nf) b[nf] = *(const bf16x8*)(lds + slotC + boff[nf]);
    bf16x8 a0 = *(const bf16x8*)(lds + slotC + aoff[0]);
    bf16x8 a1 = *(const bf16x8*)(lds + slotC + aoff[1]);
    STAGE_LO(kS, slotT);
    __builtin_amdgcn_s_setprio(1);
#pragma unroll
    for (int nf = 0; nf < 8; ++nf) {
      acc[0][nf] = __builtin_amdgcn_mfma_f32_16x16x32_bf16(a0, b[nf], acc[0][nf], 0, 0, 0);
      acc[1][nf] = __builtin_amdgcn_mfma_f32_16x16x32_bf16(a1, b[nf], acc[1][nf], 0, 0, 0);
    }
    __builtin_amdgcn_s_setprio(0);
    __builtin_amdgcn_sched_barrier(0);   // pin phase A ops before the barrier
    __builtin_amdgcn_s_barrier();
    asm volatile("" ::: "memory");

    // ---- phase B: mf 2,3 ; reuse B frags ----
    bf16x8 a2 = *(const bf16x8*)(lds + slotC + aoff[2]);
    bf16x8 a3 = *(const bf16x8*)(lds + slotC + aoff[3]);
    STAGE_HI(kS, slotT);
    __builtin_amdgcn_s_setprio(1);
#pragma unroll
    for (int nf = 0; nf < 8; ++nf) {
      acc[2][nf] = __builtin_amdgcn_mfma_f32_16x16x32_bf16(a2, b[nf], acc[2][nf], 0, 0, 0);
      acc[3][nf] = __builtin_amdgcn_mfma_f32_16x16x32_bf16(a3, b[nf], acc[3][nf], 0, 0, 0);
    }
    __builtin_amdgcn_s_setprio(0);
    __builtin_amdgcn_sched_barrier(0);   // pin phase B ops before next top barrier

    int t0 = slotC; slotC = slotN; slotN = slotT; slotT = t0;
  }
#undef STAGE_LO
#undef STAGE_HI

  // ---- register-local epilogue: acc[mf][s][j] = gate s, row r, unit t ----
  const int t = bn * 32 + wc * 16 + frow;
  float baf5[5];
#pragma unroll
  for (int s = 0; s < 5; ++s) baf5[s] = b_af[s * 256 + t];
  const float bf2 = 2.0f * b_f[t];
  float biou3[3], baiou3[3];
#pragma unroll
  for (int g = 0; g < 3; ++g) {
    biou3[g]  = b_iou[g * 256 + t];
    baiou3[g] = b_aiou[g * 256 + t];
  }

#pragma unroll
  for (int mf = 0; mf < 4; ++mf) {
#pragma unroll
    for (int j = 0; j < 4; ++j) {
      const int r = m0 + wr * 64 + mf * 16 + kq * 4 + j;
      if (r >= M_NODES) continue;
      const float mk = xmask[r];
      float ca = 0.0f;
#pragma unroll
      for (int s = 0; s < 5; ++s) {
        const float fa = acc[mf][s][j] + baf5[s] + mk * bf2;
        ca += sigm(fa) * nc[((size_t)r * 5 + s) * 256 + t];
      }
      const float iv = sigm(acc[mf][5][j] + mk * biou3[0] + baiou3[0]);
      const float ov = sigm(acc[mf][6][j] + mk * biou3[1] + baiou3[1]);
      const float uv = tanh_(acc[mf][7][j] + mk * biou3[2] + baiou3[2]);
      const float c  = iv * uv + ca;
      const float h  = ov * tanh_(c);
      out[(size_t)r * HSZ + t] = h;
      out[(size_t)M_NODES * HSZ + (size_t)r * HSZ + t] = c;
    }
  }
}

// ---------------- fallback (round-1 verified kernel, reg-staged) if ws too small ----------------
constexpr int FBM = 128, FBN = 256, FBK = 64;
constexpr int FMT = (M_NODES + FBM - 1) / FBM;  // 391
constexpr int FNT = NDIM / FBN;                 // 8
__global__ __launch_bounds__(256, 2) void gemm_fb(
    const __bf16* __restrict__ WcT,
    const float* __restrict__ x, const float* __restrict__ xmask,
    const float* __restrict__ nh, const float* __restrict__ nc,
    const float* __restrict__ b_iou, const float* __restrict__ b_f,
    const float* __restrict__ b_aiou, const float* __restrict__ b_af,
    float* __restrict__ out)
{
  __shared__ __bf16 ldsA[FBM * FBK];
  __shared__ __bf16 ldsB[FBN * FBK];

  const int bid  = blockIdx.x;
  const int wgid = (bid & 7) * (FMT * FNT / 8) + (bid >> 3);
  const int bn   = wgid & 7;
  const int m0   = (wgid >> 3) * FBM;

  const int tid  = threadIdx.x;
  const int lane = tid & 63;
  const int w    = tid >> 6;
  const int wr   = w >> 1, wc = w & 1;
  const int frow = lane & 15, kq = lane >> 4;
  const int l8   = lane >> 3, pch = lane & 7;

  const __bf16* pB[8];
  const float* xp[4]; const float* nhp[4]; float am[4]; int ac[4]; int arl[4];
#pragma unroll
  for (int j = 0; j < 4; ++j) {
    const int rl = w * 32 + j * 8 + l8;
    const int c  = pch ^ (rl & 7);
    int gr = m0 + rl; if (gr >= M_NODES) gr = M_NODES - 1;
    arl[j] = rl; ac[j] = c;
    xp[j]  = x  + (size_t)gr * 256;
    nhp[j] = nh + (size_t)gr * 1280 - 256;
    am[j]  = xmask[gr];
  }
#pragma unroll
  for (int j = 0; j < 8; ++j) {
    const int rl = w * 64 + j * 8 + l8;
    const int c  = pch ^ (rl & 7);
    pB[j] = WcT + (size_t)(bn * FBN + rl) * KDIM + c * 8;
  }

  int aoff[4][2], boff[8][2];
#pragma unroll
  for (int mf = 0; mf < 4; ++mf) {
    const int ra = wr * 64 + mf * 16 + frow;
#pragma unroll
    for (int ks = 0; ks < 2; ++ks)
      aoff[mf][ks] = ra * FBK + (((ks * 4 + kq) ^ (ra & 7)) * 8);
  }
#pragma unroll
  for (int nf = 0; nf < 8; ++nf) {
    const int rb = wc * 128 + nf * 16 + frow;
#pragma unroll
    for (int ks = 0; ks < 2; ++ks)
      boff[nf][ks] = rb * FBK + (((ks * 4 + kq) ^ (rb & 7)) * 8);
  }

  floatx4 acc[4][8];
#pragma unroll
  for (int i = 0; i < 4; ++i)
#pragma unroll
    for (int j = 0; j < 8; ++j) acc[i][j] = (floatx4)(0.0f);

  for (int kt = 0; kt < KDIM / FBK; ++kt) {
    __syncthreads();
    const int k0base = kt * FBK;
#pragma unroll
    for (int j = 0; j < 4; ++j) {
      const int k0 = k0base + ac[j] * 8;
      const float* src = (k0 < 256) ? (xp[j] + k0) : (nhp[j] + k0);
      const float sc   = (k0 < 256) ? am[j] : 1.0f;
      float4 f0 = *(const float4*)(src);
      float4 f1 = *(const float4*)(src + 4);
      bf16x8 v;
      v[0] = (__bf16)(f0.x * sc); v[1] = (__bf16)(f0.y * sc);
      v[2] = (__bf16)(f0.z * sc); v[3] = (__bf16)(f0.w * sc);
      v[4] = (__bf16)(f1.x * sc); v[5] = (__bf16)(f1.y * sc);
      v[6] = (__bf16)(f1.z * sc); v[7] = (__bf16)(f1.w * sc);
      *(bf16x8*)&ldsA[arl[j] * FBK + pch * 8] = v;
    }
#pragma unroll
    for (int j = 0; j < 8; ++j) {
      bf16x8 vb = *(const bf16x8*)pB[j];
      *(bf16x8*)&ldsB[(w * 64 + j * 8 + l8) * FBK + pch * 8] = vb;
      pB[j] += FBK;
    }
    __syncthreads();
#pragma unroll
    for (int ks = 0; ks < 2; ++ks) {
      bf16x8 a0 = *(const bf16x8*)&ldsA[aoff[0][ks]];
      bf16x8 a1 = *(const bf16x8*)&ldsA[aoff[1][ks]];
      bf16x8 a2 = *(const bf16x8*)&ldsA[aoff[2][ks]];
      bf16x8 a3 = *(const bf16x8*)&ldsA[aoff[3][ks]];
#pragma unroll
      for (int nf = 0; nf < 8; ++nf) {
        bf16x8 bb = *(const bf16x8*)&ldsB[boff[nf][ks]];
        acc[0][nf] = __builtin_amdgcn_mfma_f32_16x16x32_bf16(a0, bb, acc[0][nf], 0, 0, 0);
        acc[1][nf] = __builtin_amdgcn_mfma_f32_16x16x32_bf16(a1, bb, acc[1][nf], 0, 0, 0);
        acc[2][nf] = __builtin_amdgcn_mfma_f32_16x16x32_bf16(a2, bb, acc[2][nf], 0, 0, 0);
        acc[3][nf] = __builtin_amdgcn_mfma_f32_16x16x32_bf16(a3, bb, acc[3][nf], 0, 0, 0);
      }
    }
  }

  const int t = bn * 32 + wc * 16 + frow;
  float baf5[5];
#pragma unroll
  for (int s = 0; s < 5; ++s) baf5[s] = b_af[s * 256 + t];
  const float bf2 = 2.0f * b_f[t];
  float biou3[3], baiou3[3];
#pragma unroll
  for (int g = 0; g < 3; ++g) {
    biou3[g]  = b_iou[g * 256 + t];
    baiou3[g] = b_aiou[g * 256 + t];
  }
#pragma unroll
  for (int mf = 0; mf < 4; ++mf) {
#pragma unroll
    for (int j = 0; j < 4; ++j) {
      const int r = m0 + wr * 64 + mf * 16 + kq * 4 + j;
      if (r >= M_NODES) continue;
      const float mk = xmask[r];
      float ca = 0.0f;
#pragma unroll
      for (int s = 0; s < 5; ++s) {
        const float fa = acc[mf][s][j] + baf5[s] + mk * bf2;
        ca += sigm(fa) * nc[((size_t)r * 5 + s) * 256 + t];
      }
      const float iv = sigm(acc[mf][5][j] + mk * biou3[0] + baiou3[0]);
      const float ov = sigm(acc[mf][6][j] + mk * biou3[1] + baiou3[1]);
      const float uv = tanh_(acc[mf][7][j] + mk * biou3[2] + baiou3[2]);
      const float c  = iv * uv + ca;
      const float h  = ov * tanh_(c);
      out[(size_t)r * HSZ + t] = h;
      out[(size_t)M_NODES * HSZ + (size_t)r * HSZ + t] = c;
    }
  }
}

extern "C" void kernel_launch(void* const* d_in, const int* in_sizes, int n_in,
                              void* d_out, int out_size, void* d_ws, size_t ws_size,
                              hipStream_t stream)
{
  const float* x      = (const float*)d_in[0];
  const float* xmask  = (const float*)d_in[1];
  const float* nh     = (const float*)d_in[2];
  const float* nc     = (const float*)d_in[3];
  const float* W_iou  = (const float*)d_in[4];
  const float* b_iou  = (const float*)d_in[5];
  const float* W_f    = (const float*)d_in[6];
  const float* b_f    = (const float*)d_in[7];
  const float* W_aiou = (const float*)d_in[8];
  const float* b_aiou = (const float*)d_in[9];
  const float* W_af   = (const float*)d_in[10];
  const float* b_af   = (const float*)d_in[11];
  __bf16* WcT = (__bf16*)d_ws;
  float* out  = (float*)d_out;

  prep_weights<<<(NDIM * KDIM + 255) / 256, 256, 0, stream>>>(W_iou, W_f, W_aiou, W_af, WcT);

  if (ws_size >= WCT_BYTES + A_BYTES) {
    __bf16* Abf = (__bf16*)((char*)d_ws + WCT_BYTES);
    prep_A<<<(M_NODES * (KDIM / 8) + 255) / 256, 256, 0, stream>>>(x, xmask, nh, Abf);
    gemm_8ph<<<dim3(MT * NT), 512, 0, stream>>>(
        Abf, WcT, xmask, nc, b_iou, b_f, b_aiou, b_af, out);
  } else {
    gemm_fb<<<dim3(FMT * FNT), 256, 0, stream>>>(
        WcT, x, xmask, nh, nc, b_iou, b_f, b_aiou, b_af, out);
  }
}